// Round 1
// baseline (1084.793 us; speedup 1.0000x reference)
//
#include <hip/hip_runtime.h>

// Problem constants (from reference setup_inputs): B=8, H=512, W=512, C=16, fp32.
#define BB 8
#define HH 512
#define WW 512
#define CC 16
#define NPIX (BB * HH * WW)   // 2,097,152 pixels
#define NTOT (NPIX * CC)      // 33,554,432 floats = 128 MiB
#define KSLOTS 15             // entries per output cell: count + 15 entries = 64 B line
#define NXCD 8

// ---------------------------------------------------------------------------
// Pass 0: zero d_out (poisoned 0xAA before every timed call). Also makes the
// whole launch sequence idempotent under rocprof counter-group replay.
// ---------------------------------------------------------------------------
__global__ __launch_bounds__(256) void zero_fill_f4(float4* __restrict__ p, int n4)
{
    int i = blockIdx.x * 256 + threadIdx.x;
    if (i < n4) p[i] = make_float4(0.f, 0.f, 0.f, 0.f);
}

__global__ void zero_ws(unsigned* __restrict__ ws)
{
    if (threadIdx.x == 0) ws[0] = 0u;
}

// Overflow entry: (q, p, w) = 3 x u32, stored after a 16 B header in d_ws.
__device__ __forceinline__ void push_ovf(unsigned* ws, int cap,
                                         unsigned q, unsigned p, float w)
{
    if (cap <= 0) return;                      // no workspace: drop (never expected)
    unsigned idx = atomicAdd(&ws[0], 1u);
    if ((int)idx < cap) {
        unsigned* e = ws + 4 + 3u * idx;
        e[0] = q;
        e[1] = p;
        e[2] = __float_as_uint(w);
    }
}

// ---------------------------------------------------------------------------
// Pass 1: binning. One thread per SOURCE pixel. For each of the <=4 valid
// bilinear corners, allocate a slot in the target cell's bin (u32 atomicAdd on
// the count dword at d_out[q*16]) and store a 4 B entry encoding
// (corner, dx+128, dy+128), where (dx,dy) = source - target pixel offset.
// Weights are NOT stored; pass 2 reconstructs them bit-exactly from u[p].
// 8M u32 atomics replace 134M fp32 atomics (16x fewer ops on the L2 atomic ALU).
// ---------------------------------------------------------------------------
__global__ __launch_bounds__(256) void bin_pass(
    const float2* __restrict__ u2,
    unsigned* __restrict__ bins,          // aliases d_out
    unsigned* __restrict__ ws, int ovf_cap)
{
    // XCD-chunked swizzle: grid 8192, chunk 1024 -> each XCD owns one batch image.
    int bid = blockIdx.x;
    bid = (bid & (NXCD - 1)) * (NPIX / 256 / NXCD) + (bid >> 3);

    const int p     = bid * 256 + threadIdx.x;     // source pixel index b*H*W + y*W + x
    const int x     = p & (WW - 1);
    const int y     = (p >> 9) & (HH - 1);
    const int pbase = p & ~(HH * WW - 1);          // b*H*W

    const float2 uv  = u2[p];
    const float  sx  = (float)x + uv.x;
    const float  sy  = (float)y + uv.y;
    const float  x0f = floorf(sx);
    const float  y0f = floorf(sy);
    const int    x0  = (int)x0f;
    const int    y0  = (int)y0f;
    const float  wx  = sx - x0f;
    const float  wy  = sy - y0f;

#pragma unroll
    for (int cy = 0; cy < 2; ++cy) {
        const int Y = y0 + cy;
        if ((unsigned)Y >= (unsigned)HH) continue;          // mode='zeros'
#pragma unroll
        for (int cx = 0; cx < 2; ++cx) {
            const int X = x0 + cx;
            if ((unsigned)X >= (unsigned)WW) continue;
            const int q  = pbase + Y * WW + X;              // target pixel (same batch)
            const int dx = x - X;
            const int dy = y - Y;
            if (dx < -127 || dx > 127 || dy < -127 || dy > 127) {
                // |u| > 127: can't encode relative offset -> overflow list (exact w)
                const float w = (cx ? wx : 1.f - wx) * (cy ? wy : 1.f - wy);
                push_ovf(ws, ovf_cap, (unsigned)q, (unsigned)p, w);
                continue;
            }
            const unsigned slot = atomicAdd(&bins[(unsigned)q << 4], 1u);
            if (slot < KSLOTS) {
                bins[((unsigned)q << 4) + 1 + slot] =
                    (unsigned)(cx | (cy << 1) | ((dx + 128) << 2) | ((dy + 128) << 10));
            } else {
                // bin full (Poisson(4) tail, ~10 cells on this input) -> overflow list
                const float w = (cx ? wx : 1.f - wx) * (cy ? wy : 1.f - wy);
                push_ovf(ws, ovf_cap, (unsigned)q, (unsigned)p, w);
            }
        }
    }
}

// ---------------------------------------------------------------------------
// Pass 2: gather. 4 threads per OUTPUT pixel (one float4 of channels each).
// Reads its own bin line (count + entries, L1-broadcast across the 4-lane
// group), reconstructs exact weights from u[p] (same fp32 ops as pass 1),
// gathers grad_out[p] as coalesced 64 B lines, overwrites d_out with plain
// float4 stores. Zero atomics. Aliasing (bins == gx) is single-owner: only
// the 4 threads of pixel q touch q's 64 B line, reads precede the write.
// ---------------------------------------------------------------------------
__global__ __launch_bounds__(256) void gather_pass(
    const float4* __restrict__ gout4,
    const float2* __restrict__ u2,
    float* gx)                                   // no restrict: aliases bins
{
    // XCD-chunked swizzle: grid 32768, chunk 4096 -> each XCD owns one batch image.
    int bid = blockIdx.x;
    bid = (bid & (NXCD - 1)) * (NPIX * 4 / 256 / NXCD) + (bid >> 3);

    const int t     = bid * 256 + threadIdx.x;   // [0, NPIX*4)
    const int c4    = t & 3;                     // which float4 of the 16 channels
    const int q     = t >> 2;                    // output pixel
    const int X     = q & (WW - 1);
    const int Y     = (q >> 9) & (HH - 1);
    const int pbase = q & ~(HH * WW - 1);

    const unsigned* bins = (const unsigned*)gx;

    unsigned cnt = bins[(unsigned)q << 4];
    if (cnt > KSLOTS) cnt = KSLOTS;              // overflowed entries handled in pass 3

    float4 acc = make_float4(0.f, 0.f, 0.f, 0.f);
    for (unsigned j = 0; j < cnt; ++j) {
        const unsigned e  = bins[((unsigned)q << 4) + 1 + j];
        const int cx = e & 1;
        const int cy = (e >> 1) & 1;
        const int dx = (int)((e >> 2) & 255) - 128;
        const int dy = (int)((e >> 10) & 255) - 128;
        const int xp = X + dx;
        const int yp = Y + dy;
        const int p  = pbase + yp * WW + xp;     // source pixel

        const float2 uv  = u2[p];                // 4 lanes same addr: L1 broadcast
        const float  sxp = (float)xp + uv.x;
        const float  syp = (float)yp + uv.y;
        const float  wx  = sxp - floorf(sxp);    // bit-identical to pass 1
        const float  wy  = syp - floorf(syp);
        const float  w   = (cx ? wx : 1.f - wx) * (cy ? wy : 1.f - wy);

        const float4 g = gout4[(p << 2) + c4];   // 4 lanes x 16 B = one 64 B line
        acc.x += w * g.x;
        acc.y += w * g.y;
        acc.z += w * g.z;
        acc.w += w * g.w;
    }
    reinterpret_cast<float4*>(gx)[t] = acc;      // coalesced, non-atomic
}

// ---------------------------------------------------------------------------
// Pass 3: flush the (rare) overflow list with fp32 atomics on top of the final
// output. Runs after gather_pass so its adds are not overwritten.
// ---------------------------------------------------------------------------
__global__ __launch_bounds__(256) void ovf_pass(
    const float* __restrict__ gout,
    const unsigned* __restrict__ ws,
    float* __restrict__ gx, int cap)
{
    unsigned n = ws[0];
    if (n > (unsigned)cap) n = (unsigned)cap;
    const unsigned total  = n * 16u;
    const unsigned stride = gridDim.x * blockDim.x;
    for (unsigned i = blockIdx.x * blockDim.x + threadIdx.x; i < total; i += stride) {
        const unsigned e = i >> 4;
        const unsigned c = i & 15u;
        const unsigned q = ws[4 + 3u * e];
        const unsigned p = ws[4 + 3u * e + 1];
        const float    w = __uint_as_float(ws[4 + 3u * e + 2]);
        atomicAdd(&gx[(q << 4) + c], w * gout[(p << 4) + c]);
    }
}

extern "C" void kernel_launch(void* const* d_in, const int* in_sizes, int n_in,
                              void* d_out, int out_size, void* d_ws, size_t ws_size,
                              hipStream_t stream)
{
    const float* gout = (const float*)d_in[0];   // grad_out [B,H,W,C]
    const float* u    = (const float*)d_in[1];   // flow     [B,H,W,2]
    // d_in[2] (x) only determines output shape; unused.
    float*    gx = (float*)d_out;
    unsigned* ws = (unsigned*)d_ws;

    // Overflow capacity: 16 B header + 12 B per entry.
    const int cap = (ws && ws_size >= 64) ? (int)((ws_size - 16) / 12) : 0;

    zero_fill_f4<<<NTOT / 4 / 256, 256, 0, stream>>>((float4*)gx, NTOT / 4);
    if (cap > 0) zero_ws<<<1, 64, 0, stream>>>(ws);

    bin_pass<<<NPIX / 256, 256, 0, stream>>>((const float2*)u, (unsigned*)gx, ws, cap);
    gather_pass<<<NPIX * 4 / 256, 256, 0, stream>>>((const float4*)gout,
                                                    (const float2*)u, gx);
    if (cap > 0) ovf_pass<<<256, 256, 0, stream>>>(gout, ws, gx, cap);
}

// Round 2
// 948.756 us; speedup vs baseline: 1.1434x; 1.1434x over previous
//
#include <hip/hip_runtime.h>

// Problem constants (from reference setup_inputs): B=8, H=512, W=512, C=16, fp32.
#define BB 8
#define HH 512
#define WW 512
#define CC 16
#define HW (HH * WW)
#define RWIN 16     // y-window radius handled by row_gather; |row - y| > RWIN -> outlier_pass
#define QCAP 1024   // max hits per 2-row scan chunk = 2*512 = 1024 exactly

// ---------------------------------------------------------------------------
// row_gather: one block per (image, output row Y). Scatter-free inversion:
//   - scan u for source rows y' in [Y-RWIN, Y+RWIN] (u image = 2 MB, L2-resident
//     on the XCD that owns this image via the blockIdx swizzle below)
//   - pixels whose floor(y'+u.y) is Y or Y-1 contribute to row Y; ballot them
//     into an LDS queue (~1K hits per block out of ~17K candidates)
//   - drain queue 16 lanes/entry: coalesced 64 B grad_out line + 2 LDS
//     atomicAdds per lane into a 512x16 f32 row accumulator (32 KB)
//   - single coalesced 32 KB full-line overwrite of the output row.
// No global atomics, no zero-fill, no partial-line HBM writes.
// ---------------------------------------------------------------------------
__global__ __launch_bounds__(256) void row_gather(
    const float* __restrict__ gout,
    const float2* __restrict__ u2,
    float4* __restrict__ gx4)
{
    // bid = Y*8 + img  ->  XCD (bid % 8) == img: each XCD owns one image's
    // u (2 MB) and sliding grad_out window in its private L2.
    const int img = blockIdx.x & 7;
    const int Y   = blockIdx.x >> 3;
    const int tid = threadIdx.x;

    __shared__ float    acc[WW * CC];   // 32 KB row accumulator
    __shared__ unsigned q[QCAP];        // 4 KB hit queue (y'<<16 | x)
    __shared__ unsigned qn;

    float4* acc4 = (float4*)acc;
#pragma unroll
    for (int i = 0; i < (WW * CC / 4) / 256; ++i)       // 8 x float4 per thread
        acc4[tid + i * 256] = make_float4(0.f, 0.f, 0.f, 0.f);
    if (tid == 0) qn = 0u;
    __syncthreads();

    const float Yf  = (float)Y;
    const float Ym1 = Yf - 1.0f;
    const int   ylo = (Y - RWIN < 0) ? 0 : Y - RWIN;
    const int   yhi = (Y + RWIN > HH - 1) ? HH - 1 : Y + RWIN;
    const int   ibase = img * HW;

    for (int yp0 = ylo; yp0 <= yhi; yp0 += 2) {
        // --- scan up to 2 source rows (u only; coalesced float2) ---
#pragma unroll
        for (int dy = 0; dy < 2; ++dy) {
            const int yp = yp0 + dy;
            if (yp > yhi) continue;
#pragma unroll
            for (int half = 0; half < 2; ++half) {
                const int x = half * 256 + tid;
                const float2 uv = u2[ibase + yp * WW + x];
                const float sy  = (float)yp + uv.y;
                const float y0f = floorf(sy);
                // corner rows are y0 and y0+1; exactly one can equal Y
                if (y0f == Yf || y0f == Ym1) {
                    const unsigned pos = atomicAdd(&qn, 1u);
                    q[pos] = (unsigned)((yp << 16) | x);   // pos < 1024 = QCAP
                }
            }
        }
        __syncthreads();

        // --- drain: 16 groups x 16 channel-lanes ---
        const unsigned n   = qn;
        const int      grp = tid >> 4;
        const int      c   = tid & 15;
        for (unsigned e = (unsigned)grp; e < n; e += 16u) {
            const unsigned ent = q[e];
            const int ys = (int)(ent >> 16);
            const int xs = (int)(ent & 0xffffu);
            const int p  = ibase + ys * WW + xs;
            const float2 uv = u2[p];             // 16 lanes same addr: broadcast, L1 hit
            const float sy   = (float)ys + uv.y;
            const float y0f  = floorf(sy);
            const float fy   = sy - y0f;
            const float wrow = (y0f == Yf) ? (1.0f - fy) : fy;  // bit-exact vs reference
            const float sx   = (float)xs + uv.x;
            const float x0f  = floorf(sx);
            const float wx   = sx - x0f;
            const float g    = gout[p * CC + c] * wrow;  // 16 lanes = one 64 B line
            if (x0f >= 0.0f && x0f <= (float)(WW - 1)) {         // corner x0 valid
                const int x0 = (int)x0f;
                atomicAdd(&acc[(x0 << 4) + c], g * (1.0f - wx));
            }
            if (x0f >= -1.0f && x0f <= (float)(WW - 2)) {        // corner x0+1 valid
                const int x1 = (int)x0f + 1;
                atomicAdd(&acc[(x1 << 4) + c], g * wx);
            }
        }
        __syncthreads();
        if (tid == 0) qn = 0u;
        __syncthreads();
    }

    // --- coalesced full-line overwrite of output row Y (no zero-fill needed) ---
    const int obase = (ibase + Y * WW) * CC / 4;
#pragma unroll
    for (int i = 0; i < (WW * CC / 4) / 256; ++i)
        gx4[obase + tid + i * 256] = acc4[tid + i * 256];
}

// ---------------------------------------------------------------------------
// outlier_pass: exact handling of contributions with |target_row - y| > RWIN
// (|u.y| ~> 15; P ~ 1e-4 per pixel for this 4-sigma input -> ~hundreds of
// pixels). Runs AFTER row_gather so its atomics add on top of the final rows.
// ---------------------------------------------------------------------------
__global__ __launch_bounds__(256) void outlier_pass(
    const float* __restrict__ gout,
    const float2* __restrict__ u2,
    float* __restrict__ gx)
{
    const int p = blockIdx.x * 256 + threadIdx.x;   // [0, B*H*W)
    const int x = p & (WW - 1);
    const int y = (p >> 9) & (HH - 1);

    const float2 uv  = u2[p];
    const float  sy  = (float)y + uv.y;
    const float  y0f = floorf(sy);
    const float  fy  = sy - y0f;
    const float  yF  = (float)y;
    const float  R   = (float)RWIN;

    // corner rows r0=y0, r1=y0+1: valid in [0,H) and missed by the gather window
    const bool m0 = (y0f >= 0.0f)  && (y0f <= (float)(HH - 1)) && fabsf(y0f - yF) > R;
    const bool m1 = (y0f >= -1.0f) && (y0f <= (float)(HH - 2)) && fabsf(y0f + 1.0f - yF) > R;
    if (!m0 && !m1) return;

    const float sx  = (float)x + uv.x;
    const float x0f = floorf(sx);
    const float wx  = sx - x0f;
    const bool vx0 = (x0f >= 0.0f)  && (x0f <= (float)(WW - 1));
    const bool vx1 = (x0f >= -1.0f) && (x0f <= (float)(WW - 2));
    if (!vx0 && !vx1) return;

    const int ibase = p & ~(HW - 1);    // img * HW
    const int gbase = p * CC;
#pragma unroll
    for (int k = 0; k < 2; ++k) {
        const bool mm = k ? m1 : m0;
        if (!mm) continue;
        const float wr = k ? fy : (1.0f - fy);
        const int   r  = (int)y0f + k;              // y0f bounded when mm holds
        const int rowb = (ibase + r * WW) * CC;
        if (vx0) {
            const int   x0 = (int)x0f;
            const float w  = wr * (1.0f - wx);
            for (int c = 0; c < CC; ++c)
                atomicAdd(&gx[rowb + (x0 << 4) + c], w * gout[gbase + c]);
        }
        if (vx1) {
            const int   x1 = (int)x0f + 1;
            const float w  = wr * wx;
            for (int c = 0; c < CC; ++c)
                atomicAdd(&gx[rowb + (x1 << 4) + c], w * gout[gbase + c]);
        }
    }
}

extern "C" void kernel_launch(void* const* d_in, const int* in_sizes, int n_in,
                              void* d_out, int out_size, void* d_ws, size_t ws_size,
                              hipStream_t stream)
{
    const float* gout = (const float*)d_in[0];   // grad_out [B,H,W,C]
    const float* u    = (const float*)d_in[1];   // flow     [B,H,W,2]
    // d_in[2] (x) only determines output shape; unused. d_ws unused.
    float* gx = (float*)d_out;

    // Every output element is overwritten by row_gather -> no zero-fill.
    row_gather<<<BB * HH, 256, 0, stream>>>(gout, (const float2*)u, (float4*)gx);
    outlier_pass<<<(BB * HW) / 256, 256, 0, stream>>>(gout, (const float2*)u, gx);
}